// Round 2
// baseline (281.076 us; speedup 1.0000x reference)
//
#include <hip/hip_runtime.h>
#include <math.h>

// ---- problem constants ----
#define B_   16
#define CIN_ 256
#define COUT_ 256
#define HW_  64     // H = W = 64
#define KN_  4

typedef __bf16  bf16x8 __attribute__((ext_vector_type(8)));
typedef float   f32x4  __attribute__((ext_vector_type(4)));

// ---------------------------------------------------------------------------
// Kernel A: global average pool  x[b,ci,64,64] -> pooled[b*256+ci]
// ---------------------------------------------------------------------------
__global__ __launch_bounds__(256) void pool_kernel(const float* __restrict__ x,
                                                   float* __restrict__ pooled) {
    int bc = blockIdx.x;                       // 0..4095 = b*256+ci
    const float* p = x + (size_t)bc * 4096;
    int t = threadIdx.x;
    float s = 0.f;
#pragma unroll
    for (int i = 0; i < 16; i++) s += p[t + i * 256];
#pragma unroll
    for (int off = 32; off > 0; off >>= 1) s += __shfl_down(s, off, 64);
    __shared__ float red[4];
    if ((t & 63) == 0) red[t >> 6] = s;
    __syncthreads();
    if (t == 0) pooled[bc] = (red[0] + red[1] + red[2] + red[3]) * (1.f / 4096.f);
}

// ---------------------------------------------------------------------------
// Kernel B: routing heads -> S[b,n,9,9] = lambda * R(theta); BN fold
// ---------------------------------------------------------------------------
__global__ __launch_bounds__(256) void routing_kernel(
    const float* __restrict__ pooled,
    const float* __restrict__ w_lambda, const float* __restrict__ w_theta,
    const float* __restrict__ bn_gamma, const float* __restrict__ bn_beta,
    const float* __restrict__ bn_mean,  const float* __restrict__ bn_var,
    float* __restrict__ S, float* __restrict__ bnscale, float* __restrict__ bnshift) {
    int t = threadIdx.x;
    // fold BN (inference): scale = gamma*rsqrt(var+eps); shift = beta - mean*scale
    if (t < 256) {
        float inv = rsqrtf(bn_var[t] + 1e-5f);
        float sc = bn_gamma[t] * inv;
        bnscale[t] = sc;
        bnshift[t] = bn_beta[t] - bn_mean[t] * sc;
    }
    if (t < 64) {
        int b = t >> 2, n = t & 3;
        float zl = 0.f, zt = 0.f;
        for (int ci = 0; ci < 256; ci++) {
            float p = pooled[b * 256 + ci];
            zl += p * w_lambda[ci * 4 + n];
            zt += p * w_theta[ci * 4 + n];
        }
        float lam = 1.f / (1.f + expf(-zl));
        float th  = 3.14159265358979323846f * (zt / (1.f + fabsf(zt)));
        float xc = cosf(th), ys = sinf(th);
        float a = xc - ys, bb = xc * ys, c = xc + ys;
        float R[9][9];
#pragma unroll
        for (int i = 0; i < 9; i++)
#pragma unroll
            for (int j = 0; j < 9; j++) R[i][j] = 0.f;
        if (th >= 0.f) {
            R[0][0] = a;       R[0][1] = 1 - a;
            R[1][1] = xc - bb; R[1][2] = bb;       R[1][4] = 1 - c + bb; R[1][5] = ys - bb;
            R[2][2] = a;       R[2][5] = 1 - a;
            R[3][0] = bb;      R[3][1] = ys - bb;  R[3][3] = xc - bb;    R[3][4] = 1 - c + bb;
            R[4][4] = 1.f;
            R[5][4] = 1 - c + bb; R[5][5] = xc - bb; R[5][7] = ys - bb;  R[5][8] = bb;
            R[6][3] = 1 - a;   R[6][6] = a;
            R[7][3] = ys - bb; R[7][4] = 1 - c + bb; R[7][6] = bb;       R[7][7] = xc - bb;
            R[8][7] = 1 - a;   R[8][8] = a;
        } else {
            R[0][0] = c;       R[0][3] = 1 - c;
            R[1][0] = -bb;     R[1][1] = xc + bb;  R[1][3] = bb - ys;    R[1][4] = 1 - a - bb;
            R[2][1] = 1 - c;   R[2][2] = c;
            R[3][3] = xc + bb; R[3][4] = 1 - a - bb; R[3][6] = -bb;      R[3][7] = bb - ys;
            R[4][4] = 1.f;
            R[5][1] = bb - ys; R[5][2] = -bb;      R[5][4] = 1 - a - bb; R[5][5] = xc + bb;
            R[6][6] = c;       R[6][7] = 1 - c;
            R[7][4] = 1 - a - bb; R[7][5] = bb - ys; R[7][7] = xc + bb;  R[7][8] = -bb;
            R[8][5] = 1 - c;   R[8][8] = c;
        }
        float* Sp = S + (b * 4 + n) * 81;
#pragma unroll
        for (int p = 0; p < 9; p++)
#pragma unroll
            for (int q = 0; q < 9; q++) Sp[p * 9 + q] = lam * R[p][q];
    }
}

// ---------------------------------------------------------------------------
// Kernel C: rotated weights  rwq[b][p][co][ci] (bf16, q-major spatial-tap p)
//   rwq[b,p,co,ci] = sum_n sum_q S[b,n,p,q] * weight[n,co,ci,q]
// ---------------------------------------------------------------------------
__global__ __launch_bounds__(256) void rotw_kernel(const float* __restrict__ weight,
                                                   const float* __restrict__ S,
                                                   __bf16* __restrict__ rwq) {
    __shared__ float sl[324];
    int b = blockIdx.y;
    int t = threadIdx.x;
    // BUGFIX R1: block has 256 threads; previous `if (t < 324)` left sl[256..323]
    // uninitialized -> garbage rotation coefficients for n=3. Strided load covers all.
    for (int i = t; i < 324; i += 256) sl[i] = S[b * 324 + i];
    __syncthreads();
    int flat = blockIdx.x * 256 + t;        // 0..65535
    int co = flat >> 8, ci = flat & 255;
    float wv[4][9];
#pragma unroll
    for (int n = 0; n < 4; n++) {
        const float* wp = weight + (((size_t)n * 256 + co) * 256 + ci) * 9;
#pragma unroll
        for (int q = 0; q < 9; q++) wv[n][q] = wp[q];
    }
#pragma unroll
    for (int p = 0; p < 9; p++) {
        float s = 0.f;
#pragma unroll
        for (int n = 0; n < 4; n++) {
            const float* sp = sl + n * 81 + p * 9;
#pragma unroll
            for (int q = 0; q < 9; q++) s += sp[q] * wv[n][q];
        }
        rwq[(((size_t)b * 9 + p) * 256 + co) * 256 + ci] = (__bf16)s;
    }
}

// ---------------------------------------------------------------------------
// Kernel D: implicit-GEMM conv + fused BN/ReLU.
// Block tile: b, 64 co, 4 output rows (256 pixels). 4 waves; wave r owns row r,
// all 64 co x 64 w as 4x4 MFMA frags (16x16x32 bf16).
// K-loop: ci in chunks of 32, spatial taps q = dh*3+dw.
// LDS: xs[6 rows][66 cols][40 ci-pad] bf16 (x tile, ci-contiguous, halo cols 0/65)
//      as3[3 dw][64 co][40 ci-pad] bf16 (weight tile for one dh group)
// ---------------------------------------------------------------------------
__global__ __launch_bounds__(256, 3) void conv_kernel(
    const float* __restrict__ x, const __bf16* __restrict__ rwq,
    const float* __restrict__ bnscale, const float* __restrict__ bnshift,
    float* __restrict__ out) {
    __shared__ __attribute__((aligned(16))) __bf16 xs[6][66][40];
    __shared__ __attribute__((aligned(16))) __bf16 as3[3][64][40];

    const int t   = threadIdx.x;
    const int lane = t & 63;
    const int wv  = t >> 6;        // wave id = output row within tile
    const int l15 = lane & 15;
    const int kq  = lane >> 4;     // quad id 0..3

    const int h0  = blockIdx.x * 4;
    const int co0 = blockIdx.y * 64;
    const int b   = blockIdx.z;

    f32x4 acc[4][4];
#pragma unroll
    for (int m = 0; m < 4; m++)
#pragma unroll
        for (int n = 0; n < 4; n++) acc[m][n] = (f32x4){0.f, 0.f, 0.f, 0.f};

    // zero halo columns (cols 0 and 65) once; chunk loop only rewrites cols 1..64
    if (t < 192) {
        int rr = t / 32, c = t % 32;
        xs[rr][0][c]  = (__bf16)0.f;
        xs[rr][65][c] = (__bf16)0.f;
    }

    for (int ci0 = 0; ci0 < 256; ci0 += 32) {
        __syncthreads();   // previous chunk's compute done before overwriting xs
        // stage x tile: 6 rows x 32 ci x 64 w, float4 reads, bf16 transpose-writes
#pragma unroll
        for (int i = 0; i < 12; i++) {
            int v    = t + i * 256;     // 0..3071
            int w4   = v & 15;          // float4 index along w
            int pair = v >> 4;          // 0..191
            int rr   = pair >> 5;       // 0..5
            int c    = pair & 31;       // ci within chunk
            int hh   = h0 - 1 + rr;
            float4 val = {0.f, 0.f, 0.f, 0.f};
            if (hh >= 0 && hh < 64)
                val = *(const float4*)(x + (((size_t)(b * 256 + ci0 + c) * 64 + hh) * 64 + w4 * 4));
            int colb = w4 * 4 + 1;
            xs[rr][colb + 0][c] = (__bf16)val.x;
            xs[rr][colb + 1][c] = (__bf16)val.y;
            xs[rr][colb + 2][c] = (__bf16)val.z;
            xs[rr][colb + 3][c] = (__bf16)val.w;
        }
        for (int dh = 0; dh < 3; dh++) {
            __syncthreads();   // xs ready (dh=0) / previous dh's as3 consumed
            // stage weights for this dh: 3 dw x 64 co x 32 ci = 768 x 16B
#pragma unroll
            for (int j = 0; j < 3; j++) {
                int u   = t + j * 256;
                int dw  = u >> 8;
                int rem = u & 255;
                int co  = rem >> 2;
                int p8  = (rem & 3) * 8;
                const __bf16* src = rwq +
                    ((((size_t)b * 9 + dh * 3 + dw) * 256 + co0 + co) * 256 + ci0 + p8);
                *(uint4*)&as3[dw][co][p8] = *(const uint4*)src;
            }
            __syncthreads();
#pragma unroll
            for (int dw = 0; dw < 3; dw++) {
                bf16x8 af[4];
#pragma unroll
                for (int m = 0; m < 4; m++)
                    af[m] = *(const bf16x8*)&as3[dw][m * 16 + l15][kq * 8];
#pragma unroll
                for (int nt = 0; nt < 4; nt++) {
                    bf16x8 bfr = *(const bf16x8*)&xs[wv + dh][nt * 16 + l15 + dw][kq * 8];
#pragma unroll
                    for (int m = 0; m < 4; m++)
                        acc[m][nt] = __builtin_amdgcn_mfma_f32_16x16x32_bf16(
                            af[m], bfr, acc[m][nt], 0, 0, 0);
                }
            }
        }
    }

    // epilogue: BN + ReLU, D layout: row(co) = kq*4+reg, col(w) = l15
    const int h = h0 + wv;
#pragma unroll
    for (int m = 0; m < 4; m++) {
#pragma unroll
        for (int reg = 0; reg < 4; reg++) {
            int co = co0 + m * 16 + kq * 4 + reg;
            float sc = bnscale[co], sh = bnshift[co];
#pragma unroll
            for (int nt = 0; nt < 4; nt++) {
                int w = nt * 16 + l15;
                float v = acc[m][nt][reg] * sc + sh;
                out[(((size_t)b * 256 + co) * 64 + h) * 64 + w] = v > 0.f ? v : 0.f;
            }
        }
    }
}

// ---------------------------------------------------------------------------
extern "C" void kernel_launch(void* const* d_in, const int* in_sizes, int n_in,
                              void* d_out, int out_size, void* d_ws, size_t ws_size,
                              hipStream_t stream) {
    const float* x        = (const float*)d_in[0];
    const float* weight   = (const float*)d_in[1];
    const float* w_lambda = (const float*)d_in[2];
    const float* w_theta  = (const float*)d_in[3];
    const float* bn_gamma = (const float*)d_in[4];
    const float* bn_beta  = (const float*)d_in[5];
    const float* bn_mean  = (const float*)d_in[6];
    const float* bn_var   = (const float*)d_in[7];
    float* out = (float*)d_out;

    char* ws = (char*)d_ws;
    float*  pooled  = (float*)(ws);            // 4096 f
    float*  S       = (float*)(ws + 16384);    // 5184 f
    float*  bnscale = (float*)(ws + 40960);    // 256 f
    float*  bnshift = (float*)(ws + 45056);    // 256 f
    __bf16* rwq     = (__bf16*)(ws + 49152);   // 16*9*256*256 bf16 = 18.9 MB

    pool_kernel<<<4096, 256, 0, stream>>>(x, pooled);
    routing_kernel<<<1, 256, 0, stream>>>(pooled, w_lambda, w_theta,
                                          bn_gamma, bn_beta, bn_mean, bn_var,
                                          S, bnscale, bnshift);
    rotw_kernel<<<dim3(256, 16), 256, 0, stream>>>(weight, S, rwq);
    conv_kernel<<<dim3(16, 4, 16), 256, 0, stream>>>(x, rwq, bnscale, bnshift, out);
}